// Round 1
// baseline (1768.679 us; speedup 1.0000x reference)
//
#include <hip/hip_runtime.h>
#include <math.h>

#define TB 256

// Problem constants
// B=8, T=10, H=W=64, CIN=32, F=64, 4F=256, G=4, 3x3 SAME conv

__device__ __forceinline__ float sigmoidf_(float x) {
    return 1.0f / (1.0f + __expf(-x));
}
__device__ __forceinline__ float tanhf_(float x) {
    float e = __expf(2.0f * x);
    return 1.0f - 2.0f / (e + 1.0f);
}

// -------------------------------------------------------------------------
// conv_step: z[b, y, x, 0:256] = bias[g] + conv(x_t, kernel) + conv(h_{t-1}, rk[g])
// One block: 16x16 pixel tile, 64 of 256 output channels (cq), one batch b.
// grid = B(8) * tiles(16) * cq(4) = 512 blocks, 256 threads.
// Per thread: 4 pixels x 16 channels accumulators.
// LDS: patch[324 pos][36 stride] (18x18 halo, 32 ch) + wbuf[32][64].
// Phases: 0 = input conv (x, cin 0..31); 1,2 = recurrent conv (h ch 0..31 / 32..63).
// t==0: h == 0 -> only phase 0.
// -------------------------------------------------------------------------
__global__ __launch_bounds__(256, 2)
void conv_step(const float* __restrict__ x,
               const float* __restrict__ kern,   // (3,3,32,256)
               const float* __restrict__ rk,     // (4,3,3,64,256)
               const float* __restrict__ bias,   // (4,256)
               const int*   __restrict__ labels, // (8,)
               const float* __restrict__ outp,   // (8,10,64,64,64)  h source
               float*       __restrict__ z,      // (8,64,64,256) scratch
               int t)
{
    __shared__ float patch[324 * 36];   // 46656 B
    __shared__ float wbuf[32 * 64];     //  8192 B

    const int tid  = threadIdx.x;
    const int bid  = blockIdx.x;
    const int cq   = bid & 3;
    const int tile = (bid >> 2) & 15;
    const int b    = bid >> 6;
    const int ty = tile >> 2, tx = tile & 3;
    const int y0 = ty * 16,  x0 = tx * 16;

    const int g = labels[b];

    const int cg  = tid & 3;     // channel group within quarter (16 ch each)
    const int pg  = tid >> 2;    // pixel group 0..63
    const int ch0 = cq * 64 + cg * 16;

    // accumulators, init with bias (broadcast over pixels)
    float acc[4][16];
    {
        const float* bp = bias + g * 256 + ch0;
        #pragma unroll
        for (int j = 0; j < 16; ++j) {
            float bv = bp[j];
            #pragma unroll
            for (int q = 0; q < 4; ++q) acc[q][j] = bv;
        }
    }

    // base patch positions of this thread's 4 pixels (top-left tap)
    int pos00[4];
    #pragma unroll
    for (int q = 0; q < 4; ++q) {
        int p = q * 64 + pg;                 // pixel index in 16x16 tile
        pos00[q] = (p >> 4) * 18 + (p & 15); // row-major in 18x18 halo patch
    }

    const int nph = (t == 0) ? 1 : 3;
    for (int ph = 0; ph < nph; ++ph) {
        __syncthreads();   // previous phase's patch reads complete

        // ---- stage 18x18 halo patch, 32 channels, into LDS ----
        if (ph == 0) {
            const float* src = x + ((((size_t)b * 10 + t) << 12) << 5);
            for (int s = tid; s < 324 * 8; s += TB) {
                int pos = s >> 3, c4 = (s & 7) << 2;
                int r = pos / 18, col = pos - r * 18;
                int gy = y0 + r - 1, gx = x0 + col - 1;
                float4 v = make_float4(0.f, 0.f, 0.f, 0.f);
                if ((unsigned)gy < 64u && (unsigned)gx < 64u)
                    v = *(const float4*)&src[(((gy << 6) + gx) << 5) + c4];
                *(float4*)&patch[pos * 36 + c4] = v;
            }
        } else {
            const int f0 = (ph - 1) * 32;
            const float* src = outp + ((((size_t)b * 10 + (t - 1)) << 12) << 6) + f0;
            for (int s = tid; s < 324 * 8; s += TB) {
                int pos = s >> 3, c4 = (s & 7) << 2;
                int r = pos / 18, col = pos - r * 18;
                int gy = y0 + r - 1, gx = x0 + col - 1;
                float4 v = make_float4(0.f, 0.f, 0.f, 0.f);
                if ((unsigned)gy < 64u && (unsigned)gx < 64u)
                    v = *(const float4*)&src[(((gy << 6) + gx) << 6) + c4];
                *(float4*)&patch[pos * 36 + c4] = v;
            }
        }

        for (int k9 = 0; k9 < 9; ++k9) {
            __syncthreads();  // patch staged (k9==0) / previous wbuf reads done

            // ---- stage weight tap [32 in-ch][64 out-ch] ----
            {
                const float* wsrc;
                if (ph == 0) wsrc = kern + (k9 * 32) * 256 + cq * 64;
                else         wsrc = rk + (((size_t)(g * 9 + k9) * 64) + (ph - 1) * 32) * 256 + cq * 64;
                for (int s = tid; s < 512; s += TB) {
                    int c = s >> 4, ch4 = (s & 15) << 2;
                    *(float4*)&wbuf[(c << 6) + ch4] = *(const float4*)&wsrc[c * 256 + ch4];
                }
            }
            __syncthreads();

            const int off = (k9 / 3) * 18 + (k9 % 3);
            #pragma unroll 2
            for (int c4 = 0; c4 < 32; c4 += 4) {
                float4 xv[4];
                #pragma unroll
                for (int q = 0; q < 4; ++q)
                    xv[q] = *(const float4*)&patch[(pos00[q] + off) * 36 + c4];
                #pragma unroll
                for (int i = 0; i < 4; ++i) {
                    const float4* wp = (const float4*)&wbuf[((c4 + i) << 6) + cg * 16];
                    float4 w0 = wp[0], w1 = wp[1], w2 = wp[2], w3 = wp[3];
                    #pragma unroll
                    for (int q = 0; q < 4; ++q) {
                        float s_ = ((const float*)&xv[q])[i];
                        acc[q][0]  = fmaf(s_, w0.x, acc[q][0]);
                        acc[q][1]  = fmaf(s_, w0.y, acc[q][1]);
                        acc[q][2]  = fmaf(s_, w0.z, acc[q][2]);
                        acc[q][3]  = fmaf(s_, w0.w, acc[q][3]);
                        acc[q][4]  = fmaf(s_, w1.x, acc[q][4]);
                        acc[q][5]  = fmaf(s_, w1.y, acc[q][5]);
                        acc[q][6]  = fmaf(s_, w1.z, acc[q][6]);
                        acc[q][7]  = fmaf(s_, w1.w, acc[q][7]);
                        acc[q][8]  = fmaf(s_, w2.x, acc[q][8]);
                        acc[q][9]  = fmaf(s_, w2.y, acc[q][9]);
                        acc[q][10] = fmaf(s_, w2.z, acc[q][10]);
                        acc[q][11] = fmaf(s_, w2.w, acc[q][11]);
                        acc[q][12] = fmaf(s_, w3.x, acc[q][12]);
                        acc[q][13] = fmaf(s_, w3.y, acc[q][13]);
                        acc[q][14] = fmaf(s_, w3.z, acc[q][14]);
                        acc[q][15] = fmaf(s_, w3.w, acc[q][15]);
                    }
                }
            }
        }
    }

    // ---- epilogue: write z ----
    #pragma unroll
    for (int q = 0; q < 4; ++q) {
        int p  = q * 64 + pg;
        int py = y0 + (p >> 4), px = x0 + (p & 15);
        float* zp = z + ((((size_t)b << 12) + (py << 6) + px) << 8) + ch0;
        *(float4*)&zp[0]  = make_float4(acc[q][0],  acc[q][1],  acc[q][2],  acc[q][3]);
        *(float4*)&zp[4]  = make_float4(acc[q][4],  acc[q][5],  acc[q][6],  acc[q][7]);
        *(float4*)&zp[8]  = make_float4(acc[q][8],  acc[q][9],  acc[q][10], acc[q][11]);
        *(float4*)&zp[12] = make_float4(acc[q][12], acc[q][13], acc[q][14], acc[q][15]);
    }
}

// -------------------------------------------------------------------------
// gate_step: LSTM pointwise update.
// c_new = sig(zf)*c + sig(zi)*tanh(zg);  h = sig(zo)*tanh(c_new)
// h written to out[b,t]; c kept in ws. t==0 uses c=0 (no memset needed).
// grid = 8*4096*16 / 256 = 2048 blocks, one float4 of F per thread.
// -------------------------------------------------------------------------
__global__ __launch_bounds__(256)
void gate_step(const float* __restrict__ z,
               float*       __restrict__ c,
               float*       __restrict__ outp,
               int t)
{
    int idx = blockIdx.x * 256 + threadIdx.x;  // 524288 total
    int b   = idx >> 16;
    int rem = idx & 65535;
    int pos = rem >> 4;
    int f4  = (rem & 15) << 2;

    const float* zp = z + ((((size_t)b << 12) + pos) << 8) + f4;
    float4 zi = *(const float4*)&zp[0];
    float4 zf = *(const float4*)&zp[64];
    float4 zg = *(const float4*)&zp[128];
    float4 zo = *(const float4*)&zp[192];

    float* cp = c + ((((size_t)b << 12) + pos) << 6) + f4;
    float4 cv = make_float4(0.f, 0.f, 0.f, 0.f);
    if (t > 0) cv = *(const float4*)cp;

    float4 cn, hn;
    cn.x = sigmoidf_(zf.x) * cv.x + sigmoidf_(zi.x) * tanhf_(zg.x);
    cn.y = sigmoidf_(zf.y) * cv.y + sigmoidf_(zi.y) * tanhf_(zg.y);
    cn.z = sigmoidf_(zf.z) * cv.z + sigmoidf_(zi.z) * tanhf_(zg.z);
    cn.w = sigmoidf_(zf.w) * cv.w + sigmoidf_(zi.w) * tanhf_(zg.w);
    hn.x = sigmoidf_(zo.x) * tanhf_(cn.x);
    hn.y = sigmoidf_(zo.y) * tanhf_(cn.y);
    hn.z = sigmoidf_(zo.z) * tanhf_(cn.z);
    hn.w = sigmoidf_(zo.w) * tanhf_(cn.w);

    *(float4*)cp = cn;
    float* op = outp + ((((size_t)b * 10 + t) << 12) + pos) * 64 + f4;
    *(float4*)op = hn;
}

extern "C" void kernel_launch(void* const* d_in, const int* in_sizes, int n_in,
                              void* d_out, int out_size, void* d_ws, size_t ws_size,
                              hipStream_t stream)
{
    const float* x    = (const float*)d_in[0];
    const int*   lbl  = (const int*)  d_in[1];
    const float* kern = (const float*)d_in[2];
    const float* rk   = (const float*)d_in[3];
    const float* bias = (const float*)d_in[4];
    float* out = (float*)d_out;

    float* z = (float*)d_ws;                              // 8*4096*256 f32 = 33.5 MB
    float* c = (float*)d_ws + (size_t)8 * 4096 * 256;     // 8*4096*64  f32 =  8.4 MB

    for (int t = 0; t < 10; ++t) {
        hipLaunchKernelGGL(conv_step, dim3(512), dim3(256), 0, stream,
                           x, kern, rk, bias, lbl, out, z, t);
        hipLaunchKernelGGL(gate_step, dim3(2048), dim3(256), 0, stream,
                           z, c, out, t);
    }
}

// Round 2
// 251.450 us; speedup vs baseline: 7.0339x; 7.0339x over previous
//
#include <hip/hip_runtime.h>

// ConvLSTM2D on MI355X: fused bf16-MFMA conv (input + label-gathered recurrent)
// + in-register LSTM gates. B=8,T=10,H=W=64,CIN=32,F=64,4F=256,G=4.
//
// Per step: one kernel. Block = 256 thr (4 waves) = 8x8 pixel tile x all 256
// gate-channels, one batch b. Wave wq computes 64 px x f-channels
// [wq*16, wq*16+16) for ALL 4 gates (ch-tiles n = gate*4... i.e. co =
// gate*64 + wq*16 + lane&15), so gate math needs no cross-wave exchange.
// K = 864 (9 taps * 32 cin + 18 half-taps * 32 h-ch) in 27 mfma chunks.
// A (activations) from LDS halo [kb][100 pos][8ci]; B (weights) from global,
// pre-transposed once into MFMA-native [chunk][kb][co][8] bf16.
// h ring: bf16 double buffer in ws (halo reads cross block boundaries -> must
// not alias same-dispatch writes). c: f32 in ws, in-place (own pixels only).

typedef __attribute__((ext_vector_type(8))) short short8v;
typedef __attribute__((ext_vector_type(4))) float f32x4;
typedef unsigned short u16;

__device__ __forceinline__ u16 f2bf(float x) {
    union { float f; unsigned u; } a; a.f = x;
    unsigned r = a.u + 0x7FFFu + ((a.u >> 16) & 1u);   // RNE
    return (u16)(r >> 16);
}
__device__ __forceinline__ float sigf(float x) { return 1.0f / (1.0f + __expf(-x)); }
__device__ __forceinline__ float tanhf_(float x) {
    float e = __expf(2.0f * x);
    return 1.0f - 2.0f / (e + 1.0f);
}

// ---- prep: x f32 -> bf16 (10,485,760 elems = 2,621,440 float4) ----
__global__ __launch_bounds__(256)
void prep_x(const float* __restrict__ x, u16* __restrict__ xb) {
    size_t i = (size_t)blockIdx.x * 256 + threadIdx.x;
    for (; i < 2621440u; i += (size_t)2048 * 256) {
        float4 v = ((const float4*)x)[i];
        union { u16 u[4]; uint2 q; } o;
        o.u[0] = f2bf(v.x); o.u[1] = f2bf(v.y);
        o.u[2] = f2bf(v.z); o.u[3] = f2bf(v.w);
        ((uint2*)xb)[i] = o.q;
    }
}

// ---- prep: weights -> MFMA-native bf16  Wt[chunk][kb][co][i]=W[k][co] ----
// wt_in: 9 chunks (tap, ci=kb*8+i), 73728 elems.
// wt_rk: per g, 18 chunks (tap = c>>1, ci = (c&1)*32 + kb*8 + i), 589824 elems.
__global__ __launch_bounds__(256)
void prep_w(const float* __restrict__ kern, const float* __restrict__ rk,
            u16* __restrict__ wt_in, u16* __restrict__ wt_rk) {
    int idx = blockIdx.x * 256 + threadIdx.x;
    if (idx >= 82944) return;
    const float* s;
    u16* dst;
    if (idx < 9216) {
        int co = idx & 255, ckb = idx >> 8;          // 0..35
        int tap = ckb >> 2, kb = ckb & 3;
        s = kern + (size_t)((tap << 5) + (kb << 3)) * 256 + co;
        dst = wt_in + (size_t)idx * 8;
    } else {
        int j = idx - 9216;
        int co = j & 255, rest = j >> 8;             // 0..287
        int kb = rest & 3, gc = rest >> 2;           // gc = g*18 + c
        int g = gc / 18, cc = gc - g * 18;
        int tap = cc >> 1;
        int cib = ((cc & 1) << 5) + (kb << 3);
        s = rk + (size_t)(((g * 9 + tap) << 6) + cib) * 256 + co;
        dst = wt_rk + (size_t)j * 8;
    }
    union { u16 u[8]; uint4 q; } o;
    #pragma unroll
    for (int i = 0; i < 8; ++i) o.u[i] = f2bf(s[i * 256]);
    *(uint4*)dst = o.q;
}

// ---- fused conv + gates, one timestep ----
__global__ __launch_bounds__(256, 2)
void lstm_step(const u16* __restrict__ xb, const u16* __restrict__ wt_in,
               const u16* __restrict__ wt_rk, const float* __restrict__ bias,
               const int* __restrict__ labels,
               const u16* __restrict__ hrd,   // h_{t-1} bf16 [b][4096][64]
               u16* __restrict__ hwr,         // h_t   bf16 (other buffer)
               float* __restrict__ cst,       // c f32 [b][4096][64]
               float* __restrict__ out,       // [b][10][4096][64] f32
               int t)
{
    __shared__ short hal[6400];   // [kb<=8][100 pos][8 ci] bf16 halo

    const int tid  = threadIdx.x;
    const int lane = tid & 63;
    const int wq   = tid >> 6;                       // f-slice of 16
    const int b    = blockIdx.x >> 6;
    const int tile = blockIdx.x & 63;
    const int y0 = (tile >> 3) << 3, x0 = (tile & 7) << 3;
    const int g = labels[b];

    const int co_l = lane & 15;
    const int kbl  = lane >> 4;
    const int prow = (lane & 15) >> 3, pcol = lane & 7;
    const int aoff = prow * 10 + pcol;               // halo pos base

    // acc[m][n]: px-tile m (16 px), gate n; D row = pixel, col = channel
    f32x4 acc[4][4];
    #pragma unroll
    for (int n = 0; n < 4; ++n) {
        float bv = bias[(g << 8) + (n << 6) + (wq << 4) + co_l];
        #pragma unroll
        for (int m = 0; m < 4; ++m) acc[m][n] = (f32x4){bv, bv, bv, bv};
    }

    // ---------- phase X: input conv, K = 9 taps x 32 ci ----------
    {
        const u16* src = xb + ((size_t)(b * 10 + t) << 17);
        for (int s = tid; s < 400; s += 256) {
            int pos = s >> 2, kb = s & 3;
            int hy = pos / 10, hx = pos - hy * 10;
            int gy = y0 + hy - 1, gx = x0 + hx - 1;
            short8v v = (short8v){0,0,0,0,0,0,0,0};
            if ((unsigned)gy < 64u && (unsigned)gx < 64u)
                v = *(const short8v*)&src[(((gy << 6) + gx) << 5) + (kb << 3)];
            *(short8v*)&hal[kb * 800 + pos * 8] = v;
        }
    }
    __syncthreads();
    #pragma unroll 1
    for (int tap = 0; tap < 9; ++tap) {
        int koff = (tap / 3) * 10 + (tap % 3);
        short8v bfr[4];
        const u16* wb = wt_in + (size_t)((((tap << 2) + kbl) << 8) + (wq << 4) + co_l) * 8;
        #pragma unroll
        for (int n = 0; n < 4; ++n)
            bfr[n] = *(const short8v*)&wb[(size_t)n << 9];     // co += 64
        short8v af[4];
        int abase = kbl * 800 + (aoff + koff) * 8;
        #pragma unroll
        for (int m = 0; m < 4; ++m)
            af[m] = *(const short8v*)&hal[abase + m * 160];    // 2 rows of 8 px
        #pragma unroll
        for (int m = 0; m < 4; ++m)
            #pragma unroll
            for (int n = 0; n < 4; ++n)
                acc[m][n] = __builtin_amdgcn_mfma_f32_16x16x32_bf16(af[m], bfr[n], acc[m][n], 0, 0, 0);
    }

    // ---------- phase H: recurrent conv, K = 9 taps x 64 hch ----------
    if (t > 0) {
        __syncthreads();
        const u16* src = hrd + ((size_t)b << 18);
        for (int s = tid; s < 800; s += 256) {
            int pos = s >> 3, kb = s & 7;
            int hy = pos / 10, hx = pos - hy * 10;
            int gy = y0 + hy - 1, gx = x0 + hx - 1;
            short8v v = (short8v){0,0,0,0,0,0,0,0};
            if ((unsigned)gy < 64u && (unsigned)gx < 64u)
                v = *(const short8v*)&src[(((gy << 6) + gx) << 6) + (kb << 3)];
            *(short8v*)&hal[kb * 800 + pos * 8] = v;
        }
        __syncthreads();
        #pragma unroll 1
        for (int c = 0; c < 18; ++c) {
            int tap = c >> 1;
            int koff = (tap / 3) * 10 + (tap % 3);
            short8v bfr[4];
            const u16* wb = wt_rk + (size_t)(((((g * 18 + c) << 2) + kbl) << 8) + (wq << 4) + co_l) * 8;
            #pragma unroll
            for (int n = 0; n < 4; ++n)
                bfr[n] = *(const short8v*)&wb[(size_t)n << 9];
            short8v af[4];
            int abase = ((c & 1) * 3200) + kbl * 800 + (aoff + koff) * 8;
            #pragma unroll
            for (int m = 0; m < 4; ++m)
                af[m] = *(const short8v*)&hal[abase + m * 160];
            #pragma unroll
            for (int m = 0; m < 4; ++m)
                #pragma unroll
                for (int n = 0; n < 4; ++n)
                    acc[m][n] = __builtin_amdgcn_mfma_f32_16x16x32_bf16(af[m], bfr[n], acc[m][n], 0, 0, 0);
        }
    }

    // ---------- gates (fully in-register) + writeback ----------
    const int f = (wq << 4) + co_l;
    const int rowb = kbl << 2;
    float* cb  = cst + ((size_t)b << 18);
    float* ob  = out + ((size_t)(b * 10 + t) << 18);
    u16*   hbw = hwr + ((size_t)b << 18);
    #pragma unroll
    for (int m = 0; m < 4; ++m) {
        #pragma unroll
        for (int rr = 0; rr < 4; ++rr) {
            int p   = (m << 4) + rowb + rr;
            int pix = ((y0 + (p >> 3)) << 6) + x0 + (p & 7);
            int off = (pix << 6) + f;
            float cv = (t > 0) ? cb[off] : 0.0f;
            float zi = acc[m][0][rr], zf = acc[m][1][rr];
            float zg = acc[m][2][rr], zo = acc[m][3][rr];
            float cn = sigf(zf) * cv + sigf(zi) * tanhf_(zg);
            float hn = sigf(zo) * tanhf_(cn);
            cb[off]  = cn;
            ob[off]  = hn;
            hbw[off] = f2bf(hn);
        }
    }
}

extern "C" void kernel_launch(void* const* d_in, const int* in_sizes, int n_in,
                              void* d_out, int out_size, void* d_ws, size_t ws_size,
                              hipStream_t stream)
{
    const float* x    = (const float*)d_in[0];
    const int*   lbl  = (const int*)  d_in[1];
    const float* kern = (const float*)d_in[2];
    const float* rk   = (const float*)d_in[3];
    const float* bias = (const float*)d_in[4];
    float* out = (float*)d_out;

    // ws layout (bytes): xb 20,971,520 | hb0 4,194,304 | hb1 4,194,304 |
    // wt_in 147,456 | wt_rk 1,179,648 | c 8,388,608  -> 39,075,840 total
    u16* xb    = (u16*)d_ws;
    u16* hb0   = xb + 10485760;
    u16* hb1   = hb0 + 2097152;
    u16* wt_in = hb1 + 2097152;
    u16* wt_rk = wt_in + 73728;
    float* cst = (float*)((char*)d_ws + 30687232);

    hipLaunchKernelGGL(prep_x, dim3(2048), dim3(256), 0, stream, x, xb);
    hipLaunchKernelGGL(prep_w, dim3(324), dim3(256), 0, stream, kern, rk, wt_in, wt_rk);

    for (int t = 0; t < 10; ++t) {
        const u16* hrd = (t & 1) ? hb0 : hb1;
        u16*       hwr = (t & 1) ? hb1 : hb0;
        hipLaunchKernelGGL(lstm_step, dim3(512), dim3(256), 0, stream,
                           xb, wt_in, wt_rk, bias, lbl, hrd, hwr, cst, out, t);
    }
}

// Round 3
// 246.078 us; speedup vs baseline: 7.1875x; 1.0218x over previous
//
#include <hip/hip_runtime.h>

// ConvLSTM2D MI355X, R3: fused bf16-MFMA conv + in-register gates.
// B=8,T=10,H=W=64,CIN=32,F=64,4F=256,G=4.
// Block = 512 thr (8 waves) = 16x8 px tile x all 256 gate-channels, grid 256.
// Wave (pxh = w>>2, wq = w&3): 64 px (8x8) x f-slice [wq*16,wq*16+16) x 4 gates.
// Single barrier: stage X-halo (f32->bf16) and H-halo (bf16) into disjoint LDS,
// sync once, then 9 + 18 MFMA chunks (K=864) with compiler-pipelined weight
// loads from L2. Gates in-register; h ring bf16 double-buffered in ws; c f32.

typedef __attribute__((ext_vector_type(8))) short short8v;
typedef __attribute__((ext_vector_type(4))) float f32x4;
typedef unsigned short u16;

__device__ __forceinline__ u16 f2bf(float x) {
    union { float f; unsigned u; } a; a.f = x;
    unsigned r = a.u + 0x7FFFu + ((a.u >> 16) & 1u);   // RNE
    return (u16)(r >> 16);
}
__device__ __forceinline__ float sigf(float x) { return 1.0f / (1.0f + __expf(-x)); }
__device__ __forceinline__ float tanhf_(float x) {
    float e = __expf(2.0f * x);
    return 1.0f - 2.0f / (e + 1.0f);
}

// ---- prep: weights -> MFMA-native bf16  Wt[chunk][kb][co][i] ----
__global__ __launch_bounds__(256)
void prep_w(const float* __restrict__ kern, const float* __restrict__ rk,
            u16* __restrict__ wt_in, u16* __restrict__ wt_rk) {
    int idx = blockIdx.x * 256 + threadIdx.x;
    if (idx >= 82944) return;
    const float* s;
    u16* dst;
    if (idx < 9216) {
        int co = idx & 255, ckb = idx >> 8;          // 0..35 = tap*4+kb
        int tap = ckb >> 2, kb = ckb & 3;
        s = kern + (size_t)((tap << 5) + (kb << 3)) * 256 + co;
        dst = wt_in + (size_t)idx * 8;
    } else {
        int j = idx - 9216;
        int co = j & 255, rest = j >> 8;             // 0..287
        int kb = rest & 3, gc = rest >> 2;           // gc = g*18 + c
        int g = gc / 18, cc = gc - g * 18;
        int tap = cc >> 1;
        int cib = ((cc & 1) << 5) + (kb << 3);
        s = rk + (size_t)(((g * 9 + tap) << 6) + cib) * 256 + co;
        dst = wt_rk + (size_t)j * 8;
    }
    union { u16 u[8]; uint4 q; } o;
    #pragma unroll
    for (int i = 0; i < 8; ++i) o.u[i] = f2bf(s[i * 256]);
    *(uint4*)dst = o.q;
}

// ---- fused conv + gates, one timestep ----
__global__ __launch_bounds__(512, 2)
void lstm_step(const float* __restrict__ xf,   // (8,10,64,64,32) f32
               const u16* __restrict__ wt_in, const u16* __restrict__ wt_rk,
               const float* __restrict__ bias, const int* __restrict__ labels,
               const u16* __restrict__ hrd,    // h_{t-1} bf16 [b][4096][64]
               u16* __restrict__ hwr,          // h_t bf16 (other buffer)
               float* __restrict__ cst,        // c f32 [b][4096][64]
               float* __restrict__ out,        // (8,10,4096,64) f32
               int t)
{
    // X halo: [kb 4][180 pos][8 ci] @0 ; H halo: [kb 8][180 pos][8 ci] @5760
    __shared__ short hal[17280];   // 34,560 B

    const int tid  = threadIdx.x;
    const int lane = tid & 63;
    const int w    = tid >> 6;
    const int pxh  = w >> 2;                   // pixel half (rows 0-7 / 8-15)
    const int wq   = w & 3;                    // f-slice of 16
    const int b    = blockIdx.x >> 5;
    const int tile = blockIdx.x & 31;
    const int y0 = (tile >> 3) << 4;           // 4 y-tiles of 16 rows
    const int x0 = (tile & 7) << 3;            // 8 x-tiles of 8 cols
    const int g = labels[b];

    const int co_l = lane & 15;
    const int kbl  = lane >> 4;
    const int prow = (lane & 15) >> 3, pcol = lane & 7;

    // acc[m][n]: m = px frag (16 px = 2 rows x 8 cols), n = gate
    f32x4 acc[4][4];
    #pragma unroll
    for (int n = 0; n < 4; ++n) {
        float bv = bias[(g << 8) + (n << 6) + (wq << 4) + co_l];
        #pragma unroll
        for (int m = 0; m < 4; ++m) acc[m][n] = (f32x4){bv, bv, bv, bv};
    }

    // ---- stage X halo (f32 -> bf16), 720 slots ----
    {
        const float* src = xf + ((size_t)(b * 10 + t) << 17);
        #pragma unroll 2
        for (int s = tid; s < 720; s += 512) {
            int pos = s >> 2, kb = s & 3;
            int hy = pos / 10, hx = pos - hy * 10;
            int gy = y0 + hy - 1, gx = x0 + hx - 1;
            union { u16 u[8]; short8v v; } o;
            o.v = (short8v){0,0,0,0,0,0,0,0};
            if ((unsigned)gy < 64u && (unsigned)gx < 64u) {
                const float* p = src + (((gy << 6) + gx) << 5) + (kb << 3);
                float4 a0 = *(const float4*)p;
                float4 a1 = *(const float4*)(p + 4);
                o.u[0] = f2bf(a0.x); o.u[1] = f2bf(a0.y);
                o.u[2] = f2bf(a0.z); o.u[3] = f2bf(a0.w);
                o.u[4] = f2bf(a1.x); o.u[5] = f2bf(a1.y);
                o.u[6] = f2bf(a1.z); o.u[7] = f2bf(a1.w);
            }
            *(short8v*)&hal[kb * 1440 + pos * 8] = o.v;
        }
    }
    // ---- stage H halo (bf16), 1440 slots ----
    if (t > 0) {
        const u16* src = hrd + ((size_t)b << 18);
        #pragma unroll 3
        for (int s = tid; s < 1440; s += 512) {
            int pos = s >> 3, kb = s & 7;
            int hy = pos / 10, hx = pos - hy * 10;
            int gy = y0 + hy - 1, gx = x0 + hx - 1;
            short8v v = (short8v){0,0,0,0,0,0,0,0};
            if ((unsigned)gy < 64u && (unsigned)gx < 64u)
                v = *(const short8v*)&src[(((gy << 6) + gx) << 6) + (kb << 3)];
            *(short8v*)&hal[5760 + kb * 1440 + pos * 8] = v;
        }
    }
    __syncthreads();

    int aoffm[4];
    #pragma unroll
    for (int m = 0; m < 4; ++m)
        aoffm[m] = ((pxh << 3) + (m << 1) + prow) * 10 + pcol;

    // ---- phase X: 9 chunks ----
    #pragma unroll 3
    for (int tap = 0; tap < 9; ++tap) {
        const int koff = (tap / 3) * 10 + (tap % 3);
        const u16* wb = wt_in + (size_t)((((tap << 2) + kbl) << 8) + (wq << 4) + co_l) * 8;
        short8v bfr[4], af[4];
        #pragma unroll
        for (int n = 0; n < 4; ++n)
            bfr[n] = *(const short8v*)&wb[(size_t)n << 9];
        #pragma unroll
        for (int m = 0; m < 4; ++m)
            af[m] = *(const short8v*)&hal[kbl * 1440 + (aoffm[m] + koff) * 8];
        #pragma unroll
        for (int m = 0; m < 4; ++m)
            #pragma unroll
            for (int n = 0; n < 4; ++n)
                acc[m][n] = __builtin_amdgcn_mfma_f32_16x16x32_bf16(af[m], bfr[n], acc[m][n], 0, 0, 0);
    }

    // ---- phase H: 18 chunks ----
    if (t > 0) {
        #pragma unroll 3
        for (int c = 0; c < 18; ++c) {
            const int tap = c >> 1;
            const int koff = (tap / 3) * 10 + (tap % 3);
            const u16* wb = wt_rk + (size_t)(((((g * 18 + c) << 2) + kbl) << 8) + (wq << 4) + co_l) * 8;
            short8v bfr[4], af[4];
            #pragma unroll
            for (int n = 0; n < 4; ++n)
                bfr[n] = *(const short8v*)&wb[(size_t)n << 9];
            const int abase = 5760 + (((c & 1) << 2) + kbl) * 1440;
            #pragma unroll
            for (int m = 0; m < 4; ++m)
                af[m] = *(const short8v*)&hal[abase + (aoffm[m] + koff) * 8];
            #pragma unroll
            for (int m = 0; m < 4; ++m)
                #pragma unroll
                for (int n = 0; n < 4; ++n)
                    acc[m][n] = __builtin_amdgcn_mfma_f32_16x16x32_bf16(af[m], bfr[n], acc[m][n], 0, 0, 0);
        }
    }

    // ---- gates in-register + writeback ----
    const int f = (wq << 4) + co_l;
    float* cb  = cst + ((size_t)b << 18);
    float* ob  = out + ((size_t)(b * 10 + t) << 18);
    u16*   hbw = hwr + ((size_t)b << 18);
    #pragma unroll
    for (int m = 0; m < 4; ++m) {
        #pragma unroll
        for (int rr = 0; rr < 4; ++rr) {
            int pf = (kbl << 2) + rr;               // D row = pixel-in-frag
            int yy = y0 + (pxh << 3) + (m << 1) + (pf >> 3);
            int xx = x0 + (pf & 7);
            int off = (((yy << 6) + xx) << 6) + f;
            float cv = (t > 0) ? cb[off] : 0.0f;
            float zi = acc[m][0][rr], zf = acc[m][1][rr];
            float zg = acc[m][2][rr], zo = acc[m][3][rr];
            float cn = sigf(zf) * cv + sigf(zi) * tanhf_(zg);
            float hn = sigf(zo) * tanhf_(cn);
            cb[off]  = cn;
            ob[off]  = hn;
            hbw[off] = f2bf(hn);
        }
    }
}

extern "C" void kernel_launch(void* const* d_in, const int* in_sizes, int n_in,
                              void* d_out, int out_size, void* d_ws, size_t ws_size,
                              hipStream_t stream)
{
    const float* x    = (const float*)d_in[0];
    const int*   lbl  = (const int*)  d_in[1];
    const float* kern = (const float*)d_in[2];
    const float* rk   = (const float*)d_in[3];
    const float* bias = (const float*)d_in[4];
    float* out = (float*)d_out;

    // ws: hb0 | hb1 (bf16 h ring) | wt_in | wt_rk | c(f32)  ~18.1 MB
    u16* hb0   = (u16*)d_ws;
    u16* hb1   = hb0 + 2097152;
    u16* wt_in = hb1 + 2097152;
    u16* wt_rk = wt_in + 73728;
    float* cst = (float*)(wt_rk + 589824);

    hipLaunchKernelGGL(prep_w, dim3(324), dim3(256), 0, stream, kern, rk, wt_in, wt_rk);

    for (int t = 0; t < 10; ++t) {
        const u16* hrd = (t & 1) ? hb0 : hb1;
        u16*       hwr = (t & 1) ? hb1 : hb0;
        hipLaunchKernelGGL(lstm_step, dim3(256), dim3(512), 0, stream,
                           x, wt_in, wt_rk, bias, lbl, hrd, hwr, cst, out, t);
    }
}